// Round 1
// baseline (181.913 us; speedup 1.0000x reference)
//
#include <hip/hip_runtime.h>

typedef unsigned short u16;
typedef unsigned int   u32;
typedef __attribute__((ext_vector_type(8))) short bf16x8;
typedef __attribute__((ext_vector_type(4))) float f32x4;
typedef __attribute__((ext_vector_type(4))) u32   u32x4;

#define MFMA(a,b,c) __builtin_amdgcn_mfma_f32_16x16x32_bf16(a,b,c,0,0,0)

// B=4, S=1024, E=1024, H=16, D=64; M = B*S = 4096.

__device__ __forceinline__ u16 f2bf(float f){
  u32 u = __float_as_uint(f);
  return (u16)((u + 0x7fffu + ((u>>16)&1u)) >> 16);   // RNE, no NaN inputs here
}

// XOR swizzle for [row][64 bf16] LDS tiles (128B row stride). Returns BYTE offset.
__device__ __forceinline__ int swz(int row, int col){
  return (((row<<6) + col)<<1) ^ ((row&7)<<4);
}

__device__ __forceinline__ u32x4 pack8(f32x4 a, f32x4 b){
  u32x4 r;
  r.x = (u32)f2bf(a[0]) | ((u32)f2bf(a[1])<<16);
  r.y = (u32)f2bf(a[2]) | ((u32)f2bf(a[3])<<16);
  r.z = (u32)f2bf(b[0]) | ((u32)f2bf(b[1])<<16);
  r.w = (u32)f2bf(b[2]) | ((u32)f2bf(b[3])<<16);
  return r;
}

// C = A @ W^T + bias.  A:[4096,1024] f32 row-major, W:[1024,1024] f32 row-major ([out,in]).
// MODE 0: out bf16 scattered to [B,H,S,D] (z selects q/k/v variant; v uses Wk,bk per reference).
// MODE 1: out f32 [4096,1024] row-major.
template<int MODE>
__global__ __launch_bounds__(256) void gemm_k(
    const float* __restrict__ A0, const float* __restrict__ A1, const float* __restrict__ A2,
    const float* __restrict__ W0, const float* __restrict__ W1,
    const float* __restrict__ b0, const float* __restrict__ b1,
    u16* __restrict__ o0, u16* __restrict__ o1, u16* __restrict__ o2,
    float* __restrict__ ofin)
{
  __shared__ __align__(16) u16 As[128*64];
  __shared__ __align__(16) u16 Bs[128*64];

  const float *A, *W, *bias;
  u16* outb = nullptr;
  if (MODE==0){
    const int z = blockIdx.z;
    A    = (z==0)?A0:(z==1)?A1:A2;
    W    = (z==0)?W0:W1;
    bias = (z==0)?b0:b1;
    outb = (z==0)?o0:(z==1)?o1:o2;
  } else { A = A0; W = W0; bias = b0; }

  const int m0 = blockIdx.x<<7, n0 = blockIdx.y<<7;
  const int tid = threadIdx.x, lane = tid&63, wv = tid>>6;
  const int wm = wv>>1, wn = wv&1;
  const int r8 = tid>>3, kc = (tid&7)<<3;

  f32x4 acc[4][4] = {};

  #pragma unroll 1
  for (int kt=0; kt<1024; kt+=64){
    __syncthreads();
    #pragma unroll
    for (int i=0;i<4;++i){
      const int r = r8 + (i<<5);
      const f32x4* sa = (const f32x4*)(A + (size_t)(m0+r)*1024 + kt + kc);
      f32x4 a0 = sa[0], a1 = sa[1];
      *(u32x4*)((char*)As + swz(r,kc)) = pack8(a0,a1);
      const f32x4* sb = (const f32x4*)(W + (size_t)(n0+r)*1024 + kt + kc);
      f32x4 c0 = sb[0], c1 = sb[1];
      *(u32x4*)((char*)Bs + swz(r,kc)) = pack8(c0,c1);
    }
    __syncthreads();
    #pragma unroll
    for (int kb=0;kb<64;kb+=32){
      const int kcol = kb + ((lane>>4)<<3);
      bf16x8 af[4], bfr[4];
      #pragma unroll
      for (int t=0;t<4;++t)
        af[t]  = *(const bf16x8*)((const char*)As + swz((wm<<6) + (t<<4) + (lane&15), kcol));
      #pragma unroll
      for (int t=0;t<4;++t)
        bfr[t] = *(const bf16x8*)((const char*)Bs + swz((wn<<6) + (t<<4) + (lane&15), kcol));
      #pragma unroll
      for (int mt=0;mt<4;++mt)
        #pragma unroll
        for (int nt=0;nt<4;++nt)
          acc[mt][nt] = MFMA(af[mt], bfr[nt], acc[mt][nt]);
    }
  }

  #pragma unroll
  for (int nt=0;nt<4;++nt){
    const int col = n0 + (wn<<6) + (nt<<4) + (lane&15);
    const float bv = bias[col];
    const int hh = col>>6, dd = col&63;
    #pragma unroll
    for (int mt=0;mt<4;++mt){
      const int mb = m0 + (wm<<6) + (mt<<4) + ((lane>>4)<<2);
      f32x4 a = acc[mt][nt];
      #pragma unroll
      for (int j=0;j<4;++j){
        const int m = mb + j;
        const float val = a[j] + bv;
        if (MODE==0){
          const int bb = m>>10, ss = m&1023;
          outb[(((size_t)((bb<<4)+hh))<<16) + (ss<<6) + dd] = f2bf(val);
        } else {
          ofin[((size_t)m<<10) + col] = val;
        }
      }
    }
  }
}

// Flash attention over [B,H,S,D] bf16 heads. Block = (qt,h,b), 4 waves x 16 q-rows.
__global__ __launch_bounds__(256) void attn_k(
    const u16* __restrict__ qh, const u16* __restrict__ kh, const u16* __restrict__ vh,
    const int* __restrict__ mask, float* __restrict__ ctx)
{
  const int qt = blockIdx.x, h = blockIdx.y, b = blockIdx.z;
  __shared__ __align__(16) u16 Qs[64*64];
  __shared__ __align__(16) u16 Ks[64*64];
  __shared__ __align__(16) u16 Vt[64*64];   // transposed: Vt[d][key]
  __shared__ __align__(16) u16 Ps[4*16*64]; // per-wave P tiles

  const int tid = threadIdx.x, lane = tid&63, wv = tid>>6;
  const size_t headbase = ((size_t)((b<<4) + h))<<16;   // *S*D = *65536
  const int* maskb = mask + (b<<10);

  { // stage Q once
    const int r = tid>>2, c = (tid&3)<<4;
    const u16* Qg = qh + headbase + ((size_t)((qt<<6) + r)<<6) + c;
    *(u32x4*)((char*)Qs + swz(r,c))   = *(const u32x4*)Qg;
    *(u32x4*)((char*)Qs + swz(r,c+8)) = *(const u32x4*)(Qg+8);
  }

  f32x4 o[4] = {};
  float mr[4] = {-INFINITY,-INFINITY,-INFINITY,-INFINITY};
  float lr[4] = {0.f,0.f,0.f,0.f};

  #pragma unroll 1
  for (int kt=0; kt<16; ++kt){
    __syncthreads();
    { // stage K tile [key][d]
      const int r = tid>>2, c = (tid&3)<<4;
      const u16* Kg = kh + headbase + ((size_t)((kt<<6) + r)<<6) + c;
      *(u32x4*)((char*)Ks + swz(r,c))   = *(const u32x4*)Kg;
      *(u32x4*)((char*)Ks + swz(r,c+8)) = *(const u32x4*)(Kg+8);
    }
    { // stage V transposed: Vt[d][key]
      const int key = tid&63, d0 = (tid>>6)<<4;
      const u16* Vg = vh + headbase + ((size_t)((kt<<6)+key)<<6) + d0;
      u32x4 v0 = *(const u32x4*)Vg, v1 = *(const u32x4*)(Vg+8);
      #pragma unroll
      for (int e=0;e<8;++e){
        u16 av = (e&1) ? (u16)(v0[e>>1]>>16) : (u16)(v0[e>>1]&0xffffu);
        *(u16*)((char*)Vt + swz(d0+e, key)) = av;
        u16 bvv = (e&1) ? (u16)(v1[e>>1]>>16) : (u16)(v1[e>>1]&0xffffu);
        *(u16*)((char*)Vt + swz(d0+8+e, key)) = bvv;
      }
    }
    __syncthreads();

    // S = Q K^T : rows wv*16..+15, keys kt*64..+63
    f32x4 sc[4] = {};
    #pragma unroll
    for (int kb=0;kb<64;kb+=32){
      const int kcol = kb + ((lane>>4)<<3);
      bf16x8 aq = *(const bf16x8*)((const char*)Qs + swz((wv<<4) + (lane&15), kcol));
      #pragma unroll
      for (int nt=0;nt<4;++nt){
        bf16x8 bk_ = *(const bf16x8*)((const char*)Ks + swz((nt<<4) + (lane&15), kcol));
        sc[nt] = MFMA(aq, bk_, sc[nt]);
      }
    }

    // mask + scale
    float sv[4][4];
    int mv[4];
    #pragma unroll
    for (int nt=0;nt<4;++nt) mv[nt] = maskb[(kt<<6) + (nt<<4) + (lane&15)];
    #pragma unroll
    for (int nt=0;nt<4;++nt)
      #pragma unroll
      for (int j=0;j<4;++j){
        float s = sc[nt][j]*0.125f;
        sv[nt][j] = mv[nt] ? s : -1e30f;
      }

    // online softmax (rows live across the 16-lane group sharing lane>>4)
    float p[4][4];
    #pragma unroll
    for (int j=0;j<4;++j){
      float rm = fmaxf(fmaxf(sv[0][j],sv[1][j]), fmaxf(sv[2][j],sv[3][j]));
      rm = fmaxf(rm, __shfl_xor(rm,1));
      rm = fmaxf(rm, __shfl_xor(rm,2));
      rm = fmaxf(rm, __shfl_xor(rm,4));
      rm = fmaxf(rm, __shfl_xor(rm,8));
      const float mn = fmaxf(mr[j], rm);
      const float cf = __expf(mr[j]-mn);   // mr=-inf first iter -> 0
      mr[j] = mn;
      float rs = 0.f;
      #pragma unroll
      for (int nt=0;nt<4;++nt){
        float pv = (sv[nt][j] < -1e29f) ? 0.f : __expf(sv[nt][j]-mn);
        p[nt][j] = pv; rs += pv;
      }
      rs += __shfl_xor(rs,1); rs += __shfl_xor(rs,2);
      rs += __shfl_xor(rs,4); rs += __shfl_xor(rs,8);
      lr[j] = lr[j]*cf + rs;
      o[0][j]*=cf; o[1][j]*=cf; o[2][j]*=cf; o[3][j]*=cf;
    }

    // P -> wave-private LDS (bf16), then PV MFMA
    u16* Pw = Ps + (wv<<10);
    #pragma unroll
    for (int nt=0;nt<4;++nt)
      #pragma unroll
      for (int j=0;j<4;++j){
        const int r = ((lane>>4)<<2) + j;
        *(u16*)((char*)Pw + swz(r, (nt<<4) + (lane&15))) = f2bf(p[nt][j]);
      }
    asm volatile("s_waitcnt lgkmcnt(0)" ::: "memory");
    __builtin_amdgcn_sched_barrier(0);

    #pragma unroll
    for (int kb=0;kb<64;kb+=32){
      const int kcol = kb + ((lane>>4)<<3);
      bf16x8 pa = *(const bf16x8*)((const char*)Pw + swz(lane&15, kcol));
      #pragma unroll
      for (int nt=0;nt<4;++nt){
        bf16x8 bv2 = *(const bf16x8*)((const char*)Vt + swz((nt<<4) + (lane&15), kcol));
        o[nt] = MFMA(pa, bv2, o[nt]);
      }
    }
  }

  // epilogue: ctx[b, q, h*64+d] f32
  const int qbase = (qt<<6) + (wv<<4) + ((lane>>4)<<2);
  #pragma unroll
  for (int j=0;j<4;++j){
    const float inv = 1.f / fmaxf(lr[j], 1e-30f);
    const size_t rowoff = ((size_t)((b<<10) + qbase + j))<<10;
    #pragma unroll
    for (int nt=0;nt<4;++nt){
      const int d = (nt<<4) + (lane&15);
      ctx[rowoff + (h<<6) + d] = o[nt][j]*inv;
    }
  }
}

extern "C" void kernel_launch(void* const* d_in, const int* in_sizes, int n_in,
                              void* d_out, int out_size, void* d_ws, size_t ws_size,
                              hipStream_t stream) {
  const float* q    = (const float*)d_in[0];
  const float* k    = (const float*)d_in[1];
  const float* v    = (const float*)d_in[2];
  const int*   mask = (const int*)  d_in[3];
  const float* Wq   = (const float*)d_in[4];
  const float* bq   = (const float*)d_in[5];
  const float* Wk   = (const float*)d_in[6];
  const float* bk   = (const float*)d_in[7];
  const float* Wo   = (const float*)d_in[8];
  const float* bo   = (const float*)d_in[9];
  float* out = (float*)d_out;

  // ws layout (needs 40 MiB): qh 8MB | kh 8MB | vh 8MB | ctx 16MB (f32)
  char* ws = (char*)d_ws;
  u16*   qh  = (u16*)(ws);
  u16*   kh  = (u16*)(ws + (size_t)(8u<<20));
  u16*   vh  = (u16*)(ws + (size_t)(16u<<20));
  float* ctx = (float*)(ws + (size_t)(24u<<20));

  dim3 blk(256);
  // Q/K/V projections (V uses Wk/bk per the reference implementation)
  gemm_k<0><<<dim3(32,8,3), blk, 0, stream>>>(q, k, v, Wq, Wk, bq, bk, qh, kh, vh, nullptr);
  // attention
  attn_k<<<dim3(16,16,4), blk, 0, stream>>>(qh, kh, vh, mask, ctx);
  // output projection
  gemm_k<1><<<dim3(32,8,1), blk, 0, stream>>>(ctx, nullptr, nullptr, Wo, nullptr, bo, nullptr,
                                              nullptr, nullptr, nullptr, out);
}

// Round 2
// 151.696 us; speedup vs baseline: 1.1992x; 1.1992x over previous
//
#include <hip/hip_runtime.h>

typedef unsigned short u16;
typedef unsigned int   u32;
typedef __attribute__((ext_vector_type(8))) short bf16x8;
typedef __attribute__((ext_vector_type(4))) float f32x4;
typedef __attribute__((ext_vector_type(4))) u32   u32x4;

#define MFMA(a,b,c) __builtin_amdgcn_mfma_f32_16x16x32_bf16(a,b,c,0,0,0)

// B=4, S=1024, E=1024, H=16, D=64; M = B*S = 4096.

__device__ __forceinline__ u16 f2bf(float f){
  u32 u = __float_as_uint(f);
  return (u16)((u + 0x7fffu + ((u>>16)&1u)) >> 16);   // RNE
}

// packed f32->bf16 (RNE) via HW cvt: 2 elems/instr  [T12 recipe, m214v22]
__device__ __forceinline__ bf16x8 cvt8(f32x4 lo, f32x4 hi){
  u32 a,b,c,d;
  asm("v_cvt_pk_bf16_f32 %0, %1, %2" : "=v"(a) : "v"(lo[0]), "v"(lo[1]));
  asm("v_cvt_pk_bf16_f32 %0, %1, %2" : "=v"(b) : "v"(lo[2]), "v"(lo[3]));
  asm("v_cvt_pk_bf16_f32 %0, %1, %2" : "=v"(c) : "v"(hi[0]), "v"(hi[1]));
  asm("v_cvt_pk_bf16_f32 %0, %1, %2" : "=v"(d) : "v"(hi[2]), "v"(hi[3]));
  u32x4 u; u.x=a; u.y=b; u.z=c; u.w=d;
  return *(bf16x8*)&u;
}

// XOR swizzle for [row][64 bf16] LDS tiles (128B rows). BYTE offset.
__device__ __forceinline__ int swz(int row, int col){
  return (((row<<6) + col)<<1) ^ ((row&7)<<4);
}

// async global->LDS, 16B per lane; LDS base must be wave-uniform (HW adds lane*16)
__device__ __forceinline__ void gl16(const void* g, void* l){
  __builtin_amdgcn_global_load_lds(
      (const __attribute__((address_space(1))) u32*)g,
      (__attribute__((address_space(3))) u32*)l, 16, 0, 0);
}

// ---------------- weight fp32 -> bf16 convert (wq|wk|wo contiguous out) ----------------
__global__ __launch_bounds__(256) void cvtw_k(const float* __restrict__ wq,
    const float* __restrict__ wk, const float* __restrict__ wo, u16* __restrict__ out)
{
  const size_t i8 = (((size_t)blockIdx.x<<8) + threadIdx.x) << 3;
  const float* src;
  if      (i8 <  1048576u) src = wq + i8;
  else if (i8 <  2097152u) src = wk + (i8 - 1048576u);
  else                     src = wo + (i8 - 2097152u);
  f32x4 lo = *(const f32x4*)src, hi = *(const f32x4*)(src+4);
  *(bf16x8*)(out + i8) = cvt8(lo, hi);
}

// ---------------- GEMM: C = A @ W^T + bias ----------------
// MODE 0: A fp32 [4096,1024] (q/k/v via blockIdx.z; v uses Wk,bk per reference),
//         W bf16, out bf16 row-major [4096,1024].
// MODE 1: A bf16 [4096,1024], out f32 row-major.
// m97 structure: 128x128 tile, BK=64, global_load_lds w=16, swizzled LDS via
// pre-swizzled global source (linear LDS dest), 2-barrier K-loop.
template<int MODE>
__global__ __launch_bounds__(256) void gemm_k(
    const float* __restrict__ A0, const float* __restrict__ A1, const float* __restrict__ A2,
    const u16*  __restrict__ Ab,
    const u16*  __restrict__ W0, const u16*  __restrict__ W1,
    const float* __restrict__ b0, const float* __restrict__ b1,
    u16* __restrict__ o0, u16* __restrict__ o1, u16* __restrict__ o2,
    float* __restrict__ ofin)
{
  __shared__ __align__(16) char As[(MODE==0) ? 131072/4 : 16384];  // fp32 32KB / bf16 16KB
  __shared__ __align__(16) u16  Bs[128*64];                        // 16KB

  const float* Af = nullptr; const u16* Abf = nullptr;
  const u16* W; const float* bias;
  u16* outb = nullptr;
  if (MODE==0){
    const int z = blockIdx.z;
    Af   = (z==0)?A0:(z==1)?A1:A2;
    W    = (z==0)?W0:W1;
    bias = (z==0)?b0:b1;
    outb = (z==0)?o0:(z==1)?o1:o2;
  } else { Abf = Ab; W = W0; bias = b0; }

  const int m0 = blockIdx.x<<7, n0 = blockIdx.y<<7;
  const int tid = threadIdx.x, lane = tid&63, wv = tid>>6;
  const int wm = wv>>1, wn = wv&1;

  f32x4 acc[4][4] = {};

  #pragma unroll 1
  for (int kt=0; kt<1024; kt+=64){
    __syncthreads();
    if (MODE==0){
      // A fp32 tile 128x64 = 32KB; 8 issues/wave, 4 rows each. swzA: chunk ^= row&15.
      #pragma unroll
      for (int i=0;i<8;++i){
        const int r0  = (wv<<5) + (i<<2);
        const int row = r0 + (lane>>4);
        const int c   = ((lane&15) ^ (row&15)) << 2;   // f32 elems
        gl16(Af + (size_t)(m0+row)*1024 + kt + c, As + (r0<<8));
      }
    } else {
      // A bf16 tile 128x64 = 16KB; 4 issues/wave, 8 rows each. chunk ^= row&7.
      #pragma unroll
      for (int i=0;i<4;++i){
        const int r0  = (wv<<5) + (i<<3);
        const int row = r0 + (lane>>3);
        const int c   = ((lane&7) ^ (row&7)) << 3;     // bf16 elems
        gl16(Abf + (size_t)(m0+row)*1024 + kt + c, As + (r0<<7));
      }
    }
    // B bf16 tile
    #pragma unroll
    for (int i=0;i<4;++i){
      const int r0  = (wv<<5) + (i<<3);
      const int row = r0 + (lane>>3);
      const int c   = ((lane&7) ^ (row&7)) << 3;
      gl16(W + (size_t)(n0+row)*1024 + kt + c, (char*)Bs + (r0<<7));
    }
    __syncthreads();   // compiler drains vmcnt(0) before barrier

    #pragma unroll
    for (int kb=0;kb<64;kb+=32){
      bf16x8 af[4], bf_[4];
      #pragma unroll
      for (int t=0;t<4;++t){
        const int row = (wm<<6) + (t<<4) + (lane&15);
        if (MODE==0){
          const int ch = (kb>>2) + ((lane>>4)<<1);     // 16B chunk index (16 per row)
          f32x4 lo = *(const f32x4*)(As + (row<<8) + ((( ch   ) ^ (row&15))<<4));
          f32x4 hi = *(const f32x4*)(As + (row<<8) + (((ch+1) ^ (row&15))<<4));
          af[t] = cvt8(lo, hi);
        } else {
          const int col = kb + ((lane>>4)<<3);
          af[t] = *(const bf16x8*)(As + swz(row, col));
        }
      }
      #pragma unroll
      for (int t=0;t<4;++t){
        const int row = (wn<<6) + (t<<4) + (lane&15);
        const int col = kb + ((lane>>4)<<3);
        bf_[t] = *(const bf16x8*)((const char*)Bs + swz(row, col));
      }
      #pragma unroll
      for (int mt=0;mt<4;++mt)
        #pragma unroll
        for (int nt=0;nt<4;++nt)
          acc[mt][nt] = MFMA(af[mt], bf_[nt], acc[mt][nt]);
    }
  }

  #pragma unroll
  for (int nt=0;nt<4;++nt){
    const int col = n0 + (wn<<6) + (nt<<4) + (lane&15);
    const float bv = bias[col];
    #pragma unroll
    for (int mt=0;mt<4;++mt){
      const int mb = m0 + (wm<<6) + (mt<<4) + ((lane>>4)<<2);
      f32x4 a = acc[mt][nt];
      #pragma unroll
      for (int j=0;j<4;++j){
        const float val = a[j] + bv;
        if (MODE==0) outb[(size_t)(mb+j)*1024 + col] = f2bf(val);
        else         ofin[(size_t)(mb+j)*1024 + col] = val;
      }
    }
  }
}

// ---------------- flash attention ----------------
// qp/kp/vp bf16 row-major [B*S, E]; head h at cols h*64..h*64+63.
// Block=(qt,h,b), 4 waves x 16 q-rows, K/V tiles of 64. ctx out bf16 [B*S, E].
__global__ __launch_bounds__(256) void attn_k(
    const u16* __restrict__ qp, const u16* __restrict__ kp, const u16* __restrict__ vp,
    const int* __restrict__ mask, u16* __restrict__ ctx)
{
  const int qt = blockIdx.x, h = blockIdx.y, b = blockIdx.z;
  __shared__ __align__(16) u16 Qs[64*64];
  __shared__ __align__(16) u16 Ks[64*64];
  __shared__ __align__(16) u16 Vt[64*64];   // transposed: Vt[d][key]
  __shared__ __align__(16) u16 Ps[4*16*64]; // per-wave P tiles

  const int tid = threadIdx.x, lane = tid&63, wv = tid>>6;
  const int hc = h<<6;
  const int* maskb = mask + (b<<10);

  { // stage Q once
    const int r = tid>>2, c = (tid&3)<<4;
    const u16* Qg = qp + (size_t)((b<<10)+(qt<<6)+r)*1024 + hc + c;
    *(u32x4*)((char*)Qs + swz(r,c))   = *(const u32x4*)Qg;
    *(u32x4*)((char*)Qs + swz(r,c+8)) = *(const u32x4*)(Qg+8);
  }

  f32x4 o[4] = {};
  float mr[4] = {-INFINITY,-INFINITY,-INFINITY,-INFINITY};
  float lr[4] = {0.f,0.f,0.f,0.f};

  #pragma unroll 1
  for (int kt=0; kt<16; ++kt){
    __syncthreads();
    { // stage K tile [key][d]
      const int r = tid>>2, c = (tid&3)<<4;
      const u16* Kg = kp + (size_t)((b<<10)+(kt<<6)+r)*1024 + hc + c;
      *(u32x4*)((char*)Ks + swz(r,c))   = *(const u32x4*)Kg;
      *(u32x4*)((char*)Ks + swz(r,c+8)) = *(const u32x4*)(Kg+8);
    }
    { // stage V transposed: Vt[d][key]
      const int key = tid&63, d0 = (tid>>6)<<4;
      const u16* Vg = vp + (size_t)((b<<10)+(kt<<6)+key)*1024 + hc + d0;
      u32x4 v0 = *(const u32x4*)Vg, v1 = *(const u32x4*)(Vg+8);
      #pragma unroll
      for (int e=0;e<8;++e){
        u16 av = (e&1) ? (u16)(v0[e>>1]>>16) : (u16)(v0[e>>1]&0xffffu);
        *(u16*)((char*)Vt + swz(d0+e, key)) = av;
        u16 bvv = (e&1) ? (u16)(v1[e>>1]>>16) : (u16)(v1[e>>1]&0xffffu);
        *(u16*)((char*)Vt + swz(d0+8+e, key)) = bvv;
      }
    }
    __syncthreads();

    // S = Q K^T
    f32x4 sc[4] = {};
    #pragma unroll
    for (int kb=0;kb<64;kb+=32){
      const int kcol = kb + ((lane>>4)<<3);
      bf16x8 aq = *(const bf16x8*)((const char*)Qs + swz((wv<<4) + (lane&15), kcol));
      #pragma unroll
      for (int nt=0;nt<4;++nt){
        bf16x8 bk_ = *(const bf16x8*)((const char*)Ks + swz((nt<<4) + (lane&15), kcol));
        sc[nt] = MFMA(aq, bk_, sc[nt]);
      }
    }

    // mask + scale
    float sv[4][4];
    int mv[4];
    #pragma unroll
    for (int nt=0;nt<4;++nt) mv[nt] = maskb[(kt<<6) + (nt<<4) + (lane&15)];
    #pragma unroll
    for (int nt=0;nt<4;++nt)
      #pragma unroll
      for (int j=0;j<4;++j){
        float s = sc[nt][j]*0.125f;
        sv[nt][j] = mv[nt] ? s : -1e30f;
      }

    // online softmax
    float p[4][4];
    #pragma unroll
    for (int j=0;j<4;++j){
      float rm = fmaxf(fmaxf(sv[0][j],sv[1][j]), fmaxf(sv[2][j],sv[3][j]));
      rm = fmaxf(rm, __shfl_xor(rm,1));
      rm = fmaxf(rm, __shfl_xor(rm,2));
      rm = fmaxf(rm, __shfl_xor(rm,4));
      rm = fmaxf(rm, __shfl_xor(rm,8));
      const float mn = fmaxf(mr[j], rm);
      const float cf = __expf(mr[j]-mn);
      mr[j] = mn;
      float rs = 0.f;
      #pragma unroll
      for (int nt=0;nt<4;++nt){
        float pv = (sv[nt][j] < -1e29f) ? 0.f : __expf(sv[nt][j]-mn);
        p[nt][j] = pv; rs += pv;
      }
      rs += __shfl_xor(rs,1); rs += __shfl_xor(rs,2);
      rs += __shfl_xor(rs,4); rs += __shfl_xor(rs,8);
      lr[j] = lr[j]*cf + rs;
      o[0][j]*=cf; o[1][j]*=cf; o[2][j]*=cf; o[3][j]*=cf;
    }

    // P -> wave-private LDS (bf16), then PV MFMA
    u16* Pw = Ps + (wv<<10);
    #pragma unroll
    for (int nt=0;nt<4;++nt)
      #pragma unroll
      for (int j=0;j<4;++j){
        const int r = ((lane>>4)<<2) + j;
        *(u16*)((char*)Pw + swz(r, (nt<<4) + (lane&15))) = f2bf(p[nt][j]);
      }
    asm volatile("s_waitcnt lgkmcnt(0)" ::: "memory");
    __builtin_amdgcn_sched_barrier(0);

    #pragma unroll
    for (int kb=0;kb<64;kb+=32){
      const int kcol = kb + ((lane>>4)<<3);
      bf16x8 pa = *(const bf16x8*)((const char*)Pw + swz(lane&15, kcol));
      #pragma unroll
      for (int nt=0;nt<4;++nt){
        bf16x8 bv2 = *(const bf16x8*)((const char*)Vt + swz((nt<<4) + (lane&15), kcol));
        o[nt] = MFMA(pa, bv2, o[nt]);
      }
    }
  }

  // epilogue: ctx bf16 [B*S, E]
  const int qbase = (qt<<6) + (wv<<4) + ((lane>>4)<<2);
  #pragma unroll
  for (int j=0;j<4;++j){
    const float inv = 1.f / fmaxf(lr[j], 1e-30f);
    u16* crow = ctx + (size_t)((b<<10)+qbase+j)*1024 + hc;
    #pragma unroll
    for (int nt=0;nt<4;++nt)
      crow[(nt<<4) + (lane&15)] = f2bf(o[nt][j]*inv);
  }
}

extern "C" void kernel_launch(void* const* d_in, const int* in_sizes, int n_in,
                              void* d_out, int out_size, void* d_ws, size_t ws_size,
                              hipStream_t stream) {
  const float* q    = (const float*)d_in[0];
  const float* k    = (const float*)d_in[1];
  const float* v    = (const float*)d_in[2];
  const int*   mask = (const int*)  d_in[3];
  const float* Wq   = (const float*)d_in[4];
  const float* bq   = (const float*)d_in[5];
  const float* Wk   = (const float*)d_in[6];
  const float* bk   = (const float*)d_in[7];
  const float* Wo   = (const float*)d_in[8];
  const float* bo   = (const float*)d_in[9];
  float* out = (float*)d_out;

  // ws layout (<= 40 MiB): wqb 2M | wkb 2M | wob 2M | qp 8M | kp 8M | vp 8M | ctx 8M
  char* ws = (char*)d_ws;
  u16* wqb  = (u16*)(ws);
  u16* wkb  = (u16*)(ws +  2097152);
  u16* wob  = (u16*)(ws +  4194304);
  u16* qp   = (u16*)(ws +  6291456);
  u16* kp   = (u16*)(ws + 14680064);
  u16* vp   = (u16*)(ws + 23068672);
  u16* ctxb = (u16*)(ws + 31457280);

  dim3 blk(256);
  cvtw_k<<<1536, blk, 0, stream>>>(Wq, Wk, Wo, wqb);
  // Q/K/V projections (V uses Wk/bk per reference)
  gemm_k<0><<<dim3(32,8,3), blk, 0, stream>>>(q, k, v, nullptr, wqb, wkb, bq, bk,
                                              qp, kp, vp, nullptr);
  attn_k<<<dim3(16,16,4), blk, 0, stream>>>(qp, kp, vp, mask, ctxb);
  gemm_k<1><<<dim3(32,8,1), blk, 0, stream>>>(nullptr, nullptr, nullptr, ctxb, wob, nullptr,
                                              bo, nullptr, nullptr, nullptr, nullptr, out);
}

// Round 3
// 122.694 us; speedup vs baseline: 1.4827x; 1.2364x over previous
//
#include <hip/hip_runtime.h>

typedef unsigned short u16;
typedef unsigned int   u32;
typedef __attribute__((ext_vector_type(8))) short bf16x8;
typedef __attribute__((ext_vector_type(4))) float f32x4;
typedef __attribute__((ext_vector_type(4))) u32   u32x4;

#define MFMA(a,b,c) __builtin_amdgcn_mfma_f32_16x16x32_bf16(a,b,c,0,0,0)

// B=4, S=1024, E=1024, H=16, D=64; M = B*S = 4096.

__device__ __forceinline__ u16 f2bf(float f){
  u32 u = __float_as_uint(f);
  return (u16)((u + 0x7fffu + ((u>>16)&1u)) >> 16);   // RNE
}

__device__ __forceinline__ bf16x8 cvt8(f32x4 lo, f32x4 hi){
  u32 a,b,c,d;
  asm("v_cvt_pk_bf16_f32 %0, %1, %2" : "=v"(a) : "v"(lo[0]), "v"(lo[1]));
  asm("v_cvt_pk_bf16_f32 %0, %1, %2" : "=v"(b) : "v"(lo[2]), "v"(lo[3]));
  asm("v_cvt_pk_bf16_f32 %0, %1, %2" : "=v"(c) : "v"(hi[0]), "v"(hi[1]));
  asm("v_cvt_pk_bf16_f32 %0, %1, %2" : "=v"(d) : "v"(hi[2]), "v"(hi[3]));
  u32x4 u; u.x=a; u.y=b; u.z=c; u.w=d;
  return *(bf16x8*)&u;
}

// XOR swizzle for [row][64 bf16] LDS tiles (128B rows). BYTE offset.
__device__ __forceinline__ int swz(int row, int col){
  return (((row<<6) + col)<<1) ^ ((row&7)<<4);
}

// async global->LDS, 16B/lane; LDS dest wave-uniform (HW adds lane*16)
__device__ __forceinline__ void gl16(const void* g, void* l){
  __builtin_amdgcn_global_load_lds(
      (const __attribute__((address_space(1))) u32*)g,
      (__attribute__((address_space(3))) u32*)l, 16, 0, 0);
}

// stage 128x64 bf16 tile (rows pre-offset; ldg elems). Source-side swizzle ^(row&7).
__device__ __forceinline__ void stage_bf16(const u16* g, size_t ldg, char* lds, int wv, int lane){
  #pragma unroll
  for (int i=0;i<4;++i){
    const int r0 = (wv<<5) + (i<<3);
    const int row = r0 + (lane>>3);
    const int c = ((lane&7) ^ (row&7)) << 3;
    gl16(g + (size_t)row*ldg + c, lds + (r0<<7));
  }
}
// stage 128x64 f32 tile (256B rows, 16 chunks). Source-side swizzle ^(row&15).
__device__ __forceinline__ void stage_f32(const float* g, size_t ldg, char* lds, int wv, int lane){
  #pragma unroll
  for (int i=0;i<8;++i){
    const int r0 = (wv<<5) + (i<<2);
    const int row = r0 + (lane>>4);
    const int c = ((lane&15) ^ (row&15)) << 2;
    gl16(g + (size_t)row*ldg + c, lds + (r0<<8));
  }
}

__device__ __forceinline__ bf16x8 frag_bf16(const char* lds, int row, int kcol){
  return *(const bf16x8*)(lds + swz(row,kcol));
}
__device__ __forceinline__ bf16x8 frag_f32c(const char* lds, int row, int kb, int lane){
  const int ch = (kb>>2) + ((lane>>4)<<1);
  f32x4 lo = *(const f32x4*)(lds + (row<<8) + ((( ch   ) ^ (row&15))<<4));
  f32x4 hi = *(const f32x4*)(lds + (row<<8) + (((ch+1) ^ (row&15))<<4));
  return cvt8(lo, hi);
}

// ---------------- weight fp32 -> bf16 (wq|wk|wo contiguous) ----------------
__global__ __launch_bounds__(256) void cvtw_k(const float* __restrict__ wq,
    const float* __restrict__ wk, const float* __restrict__ wo, u16* __restrict__ out)
{
  const size_t i8 = (((size_t)blockIdx.x<<8) + threadIdx.x) << 3;
  const float* src;
  if      (i8 <  1048576u) src = wq + i8;
  else if (i8 <  2097152u) src = wk + (i8 - 1048576u);
  else                     src = wo + (i8 - 2097152u);
  f32x4 lo = *(const f32x4*)src, hi = *(const f32x4*)(src+4);
  *(bf16x8*)(out + i8) = cvt8(lo, hi);
}

// ---------------- GEMM family: C = A @ B^T (+bias) ----------------
// V=0: A=f32 input (q/k by z), B=bf16 W, bias[n], out bf16 [4096,1024]
// V=1: A=bf16 Wk,  B=f32 v-input, bias[m], out bf16 vt [1024,4096]
// V=2: A=bf16 ctx, B=bf16 Wo,    bias[n], out f32 [4096,1024]
template<int V>
__global__ __launch_bounds__(256) void gemm_k(
    const float* __restrict__ X0, const float* __restrict__ X1,
    const u16* __restrict__ B0, const u16* __restrict__ B1,
    const float* __restrict__ bias0, const float* __restrict__ bias1,
    u16* __restrict__ o0, u16* __restrict__ o1, float* __restrict__ of)
{
  constexpr bool AF = (V==0);   // A operand fp32
  constexpr bool BF = (V==1);   // B operand fp32
  __shared__ __align__(16) char As[AF?32768:16384];
  __shared__ __align__(16) char Bs[BF?32768:16384];

  const float* Xa=nullptr; const u16* Aa=nullptr;
  const float* Xb=nullptr; const u16* Bb=nullptr;
  const float* bias; u16* outb=nullptr;
  if (V==0){
    const int z = blockIdx.z;
    Xa = z?X1:X0; Bb = z?B1:B0; bias = z?bias1:bias0; outb = z?o1:o0;
  } else if (V==1){ Aa = B0; Xb = X0; bias = bias0; outb = o0; }
  else            { Aa = B0; Bb = B1; bias = bias0; }

  const int m0 = blockIdx.x<<7, n0 = blockIdx.y<<7;
  const int tid = threadIdx.x, lane = tid&63, wv = tid>>6;
  const int wm = wv>>1, wn = wv&1;

  f32x4 acc[4][4] = {};

  #pragma unroll 1
  for (int kt=0; kt<1024; kt+=64){
    __syncthreads();
    if (AF) stage_f32 (Xa + (size_t)m0*1024 + kt, 1024, As, wv, lane);
    else    stage_bf16(Aa + (size_t)m0*1024 + kt, 1024, As, wv, lane);
    if (BF) stage_f32 (Xb + (size_t)n0*1024 + kt, 1024, Bs, wv, lane);
    else    stage_bf16(Bb + (size_t)n0*1024 + kt, 1024, Bs, wv, lane);
    __syncthreads();

    #pragma unroll
    for (int kb=0;kb<64;kb+=32){
      const int kcol = kb + ((lane>>4)<<3);
      bf16x8 af[4], bf_[4];
      #pragma unroll
      for (int t=0;t<4;++t){
        const int row = (wm<<6) + (t<<4) + (lane&15);
        af[t] = AF ? frag_f32c(As, row, kb, lane) : frag_bf16(As, row, kcol);
      }
      #pragma unroll
      for (int t=0;t<4;++t){
        const int row = (wn<<6) + (t<<4) + (lane&15);
        bf_[t] = BF ? frag_f32c(Bs, row, kb, lane) : frag_bf16(Bs, row, kcol);
      }
      #pragma unroll
      for (int mt=0;mt<4;++mt)
        #pragma unroll
        for (int nt=0;nt<4;++nt)
          acc[mt][nt] = MFMA(af[mt], bf_[nt], acc[mt][nt]);
    }
  }

  f32x4 bmv[4];
  if (V==1){
    #pragma unroll
    for (int mt=0;mt<4;++mt)
      bmv[mt] = *(const f32x4*)(bias + m0 + (wm<<6) + (mt<<4) + ((lane>>4)<<2));
  }
  #pragma unroll
  for (int nt=0;nt<4;++nt){
    const int col = n0 + (wn<<6) + (nt<<4) + (lane&15);
    const float bvn = (V==1) ? 0.f : bias[col];
    #pragma unroll
    for (int mt=0;mt<4;++mt){
      const int mb = m0 + (wm<<6) + (mt<<4) + ((lane>>4)<<2);
      f32x4 a = acc[mt][nt];
      #pragma unroll
      for (int j=0;j<4;++j){
        const float val = a[j] + ((V==1) ? bmv[mt][j] : bvn);
        if      (V==2) of  [(size_t)(mb+j)*1024 + col] = val;
        else if (V==1) outb[(size_t)(mb+j)*4096 + col] = f2bf(val);
        else           outb[(size_t)(mb+j)*1024 + col] = f2bf(val);
      }
    }
  }
}

// ---------------- flash attention (fixed-max softmax) ----------------
// qp/kp bf16 [B*S, E]; vt bf16 [E, B*S] (head-transposed V). ctx bf16 [B*S, E].
// Block: 128 q-rows x (h,b); 4 waves x 32 rows. KV tiles of 64, double-buffered.
__global__ __launch_bounds__(256) void attn_k(
    const u16* __restrict__ qp, const u16* __restrict__ kp, const u16* __restrict__ vt,
    const int* __restrict__ mask, u16* __restrict__ ctx)
{
  // XCD-chunked swizzle (512 blocks, 8 XCDs): keep one (b,h)'s 8 q-tiles on one XCD
  const int bid = blockIdx.x;
  const int wg  = (bid&7)*64 + (bid>>3);
  const int qt = wg&7, h = (wg>>3)&15, b = wg>>7;

  __shared__ __align__(16) u16 Qs[128*64];     // 16KB
  __shared__ __align__(16) u16 Ks[2][64*64];   // 16KB
  __shared__ __align__(16) u16 Vs[2][64*64];   // 16KB  (rows=d, cols=key)
  __shared__ __align__(16) u16 Ps[4*32*64];    // 16KB  per-wave P
  __shared__ float biasl[1024];                // 4KB   mask bias

  const int tid = threadIdx.x, lane = tid&63, wv = tid>>6;
  const int hc = h<<6;

  // mask -> additive bias (exp(-1e30)=0 kills masked keys exactly)
  {
    const int4 mv = *(const int4*)(mask + (b<<10) + (tid<<2));
    float* bl = biasl + (tid<<2);
    bl[0] = mv.x ? 0.f : -1e30f;
    bl[1] = mv.y ? 0.f : -1e30f;
    bl[2] = mv.z ? 0.f : -1e30f;
    bl[3] = mv.w ? 0.f : -1e30f;
  }

  // stage Q (128 rows x 64 d)
  {
    const u16* Qg = qp + ((size_t)((b<<10) + (qt<<7)))*1024 + hc;
    #pragma unroll
    for (int i=0;i<4;++i){
      const int r0 = (wv<<5) + (i<<3);
      const int row = r0 + (lane>>3);
      const int c = ((lane&7) ^ (row&7)) << 3;
      gl16(Qg + (size_t)row*1024 + c, (char*)Qs + (r0<<7));
    }
  }

  const u16* Kg = kp + ((size_t)(b<<10))*1024 + hc;          // + (kt*64+row)*1024
  const u16* Vg = vt + ((size_t)hc)*4096 + (b<<10);          // + d*4096 + kt*64

  // stage K/V tile kt into buffer bi
  auto stageKV = [&](int kt2, int bi){
    #pragma unroll
    for (int i=0;i<2;++i){
      const int r0 = (wv<<4) + (i<<3);
      const int row = r0 + (lane>>3);
      const int c = ((lane&7) ^ (row&7)) << 3;
      gl16(Kg + (size_t)((kt2<<6) + row)*1024 + c, (char*)Ks[bi] + (r0<<7));
      gl16(Vg + (size_t)row*4096 + (kt2<<6) + c,  (char*)Vs[bi] + (r0<<7));
    }
  };
  stageKV(0, 0);
  __syncthreads();

  f32x4 o[2][4] = {};
  float lr[2][4] = {};
  u16* Pw = Ps + (wv<<11);
  int cur = 0;

  #pragma unroll 1
  for (int kt=0; kt<16; ++kt){
    if (kt<15) stageKV(kt+1, cur^1);
    const char* Kc = (const char*)Ks[cur];
    const char* Vc = (const char*)Vs[cur];

    // S = Q K^T  (2 q-subtiles x 4 key-subtiles)
    f32x4 sc[2][4] = {};
    #pragma unroll
    for (int kb=0;kb<64;kb+=32){
      const int kcol = kb + ((lane>>4)<<3);
      bf16x8 kf[4];
      #pragma unroll
      for (int nt=0;nt<4;++nt) kf[nt] = frag_bf16(Kc, (nt<<4)+(lane&15), kcol);
      #pragma unroll
      for (int sub=0;sub<2;++sub){
        bf16x8 aq = frag_bf16((const char*)Qs, (wv<<5)+(sub<<4)+(lane&15), kcol);
        #pragma unroll
        for (int nt=0;nt<4;++nt) sc[sub][nt] = MFMA(aq, kf[nt], sc[sub][nt]);
      }
    }

    // p = exp(s/8 + bias); masked -> exact 0. No max, no rescale.
    float bv4[4];
    #pragma unroll
    for (int nt=0;nt<4;++nt) bv4[nt] = biasl[(kt<<6)+(nt<<4)+(lane&15)];
    #pragma unroll
    for (int sub=0;sub<2;++sub)
      #pragma unroll
      for (int nt=0;nt<4;++nt){
        f32x4 s = sc[sub][nt];
        #pragma unroll
        for (int j=0;j<4;++j){
          const float p = __expf(fmaf(s[j], 0.125f, bv4[nt]));
          lr[sub][j] += p;
          *(u16*)((char*)Pw + swz((sub<<4)+((lane>>4)<<2)+j, (nt<<4)+(lane&15))) = f2bf(p);
        }
      }
    asm volatile("s_waitcnt lgkmcnt(0)" ::: "memory");
    __builtin_amdgcn_sched_barrier(0);

    // O += P V
    #pragma unroll
    for (int kb=0;kb<64;kb+=32){
      const int kcol = kb + ((lane>>4)<<3);
      bf16x8 vf[4];
      #pragma unroll
      for (int nt=0;nt<4;++nt) vf[nt] = frag_bf16(Vc, (nt<<4)+(lane&15), kcol);
      #pragma unroll
      for (int sub=0;sub<2;++sub){
        bf16x8 pa = frag_bf16((const char*)Pw, (sub<<4)+(lane&15), kcol);
        #pragma unroll
        for (int nt=0;nt<4;++nt) o[sub][nt] = MFMA(pa, vf[nt], o[sub][nt]);
      }
    }
    __syncthreads();
    cur ^= 1;
  }

  // epilogue: normalize by deferred row-sum, write ctx bf16
  #pragma unroll
  for (int sub=0;sub<2;++sub)
    #pragma unroll
    for (int j=0;j<4;++j){
      float s = lr[sub][j];
      s += __shfl_xor(s,1); s += __shfl_xor(s,2);
      s += __shfl_xor(s,4); s += __shfl_xor(s,8);
      const float inv = 1.f / fmaxf(s, 1e-30f);
      const int row = (qt<<7) + (wv<<5) + (sub<<4) + ((lane>>4)<<2) + j;
      u16* crow = ctx + ((size_t)((b<<10)+row))*1024 + hc;
      #pragma unroll
      for (int nt=0;nt<4;++nt)
        crow[(nt<<4)+(lane&15)] = f2bf(o[sub][nt][j]*inv);
    }
}

extern "C" void kernel_launch(void* const* d_in, const int* in_sizes, int n_in,
                              void* d_out, int out_size, void* d_ws, size_t ws_size,
                              hipStream_t stream) {
  const float* q    = (const float*)d_in[0];
  const float* k    = (const float*)d_in[1];
  const float* v    = (const float*)d_in[2];
  const int*   mask = (const int*)  d_in[3];
  const float* Wq   = (const float*)d_in[4];
  const float* bq   = (const float*)d_in[5];
  const float* Wk   = (const float*)d_in[6];
  const float* bk   = (const float*)d_in[7];
  const float* Wo   = (const float*)d_in[8];
  const float* bo   = (const float*)d_in[9];
  float* out = (float*)d_out;

  // ws: wqb 2M | wkb 2M | wob 2M | qp 8M | kp 8M | vt 8M | ctx 8M  = 38 MiB
  char* ws = (char*)d_ws;
  u16* wqb  = (u16*)(ws);
  u16* wkb  = (u16*)(ws +  2097152);
  u16* wob  = (u16*)(ws +  4194304);
  u16* qp   = (u16*)(ws +  6291456);
  u16* kp   = (u16*)(ws + 14680064);
  u16* vtb  = (u16*)(ws + 23068672);
  u16* ctxb = (u16*)(ws + 31457280);

  dim3 blk(256);
  cvtw_k<<<1536, blk, 0, stream>>>(Wq, Wk, Wo, wqb);
  // q,k projections -> row-major heads
  gemm_k<0><<<dim3(32,8,2), blk, 0, stream>>>(q, k, wqb, wkb, bq, bk, qp, kp, nullptr);
  // v projection, transposed output: vt[E][B*S] = Wk @ v^T + bk  (reference uses Wk/bk for v)
  gemm_k<1><<<dim3(8,32),   blk, 0, stream>>>(v, nullptr, wkb, nullptr, bk, nullptr,
                                              vtb, nullptr, nullptr);
  attn_k<<<512, blk, 0, stream>>>(qp, kp, vtb, mask, ctxb);
  gemm_k<2><<<dim3(32,8),   blk, 0, stream>>>(nullptr, nullptr, ctxb, wob, bo, nullptr,
                                              nullptr, nullptr, out);
}

// Round 6
// 115.040 us; speedup vs baseline: 1.5813x; 1.0665x over previous
//
#include <hip/hip_runtime.h>

typedef unsigned short u16;
typedef unsigned int   u32;
typedef __attribute__((ext_vector_type(8))) short bf16x8;
typedef __attribute__((ext_vector_type(4))) float f32x4;
typedef __attribute__((ext_vector_type(4))) u32   u32x4;

#define MFMA(a,b,c) __builtin_amdgcn_mfma_f32_16x16x32_bf16(a,b,c,0,0,0)

// B=4, S=1024, E=1024, H=16, D=64; M = B*S = 4096.

__device__ __forceinline__ u16 f2bf(float f){
  u32 u = __float_as_uint(f);
  return (u16)((u + 0x7fffu + ((u>>16)&1u)) >> 16);   // RNE
}
__device__ __forceinline__ u32 cvtpk(float lo, float hi){
  u32 r; asm("v_cvt_pk_bf16_f32 %0, %1, %2" : "=v"(r) : "v"(lo), "v"(hi)); return r;
}
__device__ __forceinline__ bf16x8 cvt8(f32x4 lo, f32x4 hi){
  u32x4 u;
  u.x = cvtpk(lo[0],lo[1]); u.y = cvtpk(lo[2],lo[3]);
  u.z = cvtpk(hi[0],hi[1]); u.w = cvtpk(hi[2],hi[3]);
  return *(bf16x8*)&u;
}

// XOR swizzle for [row][64 bf16] LDS tiles (128B rows). BYTE offset.
__device__ __forceinline__ int swz(int row, int col){
  return (((row<<6) + col)<<1) ^ ((row&7)<<4);
}

// async global->LDS, 16B/lane; LDS dest wave-uniform (HW adds lane*16)
__device__ __forceinline__ void gl16(const void* g, void* l){
  __builtin_amdgcn_global_load_lds(
      (const __attribute__((address_space(1))) u32*)g,
      (__attribute__((address_space(3))) u32*)l, 16, 0, 0);
}

// stage ROWSx64 bf16 tile; source-side swizzle ^(row&7) on 16B chunks.
template<int ROWS>
__device__ __forceinline__ void stage_bf16(const u16* g, size_t ldg, char* lds, int wv, int lane){
  #pragma unroll
  for (int i=0;i<ROWS/32;++i){
    const int r0 = wv*(ROWS/4) + (i<<3);
    const int row = r0 + (lane>>3);
    const int c = ((lane&7) ^ (row&7)) << 3;
    gl16(g + (size_t)row*ldg + c, lds + (r0<<7));
  }
}
// stage ROWSx64 f32 tile (256B rows); source swizzle ^(row&15).
template<int ROWS>
__device__ __forceinline__ void stage_f32(const float* g, size_t ldg, char* lds, int wv, int lane){
  #pragma unroll
  for (int i=0;i<ROWS/16;++i){
    const int r0 = wv*(ROWS/4) + (i<<2);
    const int row = r0 + (lane>>4);
    const int c = ((lane&15) ^ (row&15)) << 2;
    gl16(g + (size_t)row*ldg + c, lds + (r0<<8));
  }
}

__device__ __forceinline__ bf16x8 frag_bf16(const char* lds, int row, int kcol){
  return *(const bf16x8*)(lds + swz(row,kcol));
}
__device__ __forceinline__ bf16x8 frag_f32c(const char* lds, int row, int kb, int lane){
  const int ch = (kb>>2) + ((lane>>4)<<1);
  f32x4 lo = *(const f32x4*)(lds + (row<<8) + ((( ch   ) ^ (row&15))<<4));
  f32x4 hi = *(const f32x4*)(lds + (row<<8) + (((ch+1) ^ (row&15))<<4));
  return cvt8(lo, hi);
}

// ---------------- weight fp32 -> bf16 (wq|wk|wo contiguous) ----------------
__global__ __launch_bounds__(256) void cvtw_k(const float* __restrict__ wq,
    const float* __restrict__ wk, const float* __restrict__ wo, u16* __restrict__ out)
{
  const size_t i8 = (((size_t)blockIdx.x<<8) + threadIdx.x) << 3;
  const float* src;
  if      (i8 <  1048576u) src = wq + i8;
  else if (i8 <  2097152u) src = wk + (i8 - 1048576u);
  else                     src = wo + (i8 - 2097152u);
  f32x4 lo = *(const f32x4*)src, hi = *(const f32x4*)(src+4);
  *(bf16x8*)(out + i8) = cvt8(lo, hi);
}

// ---------------- GEMM family: C = A @ B^T (+bias) ----------------
// V=0: A=f32 q/k (z), B=bf16 Wq/Wk, BN=128, out bf16 [4096,1024]
// V=1: A=bf16 Wk,  B=f32 v, BN=64, bias[m], out bf16 vt [1024,4096]
// V=2: A=bf16 ctx, B=bf16 Wo, BN=64, out f32 [4096,1024]
template<int V>
__global__ __launch_bounds__(256) void gemm_k(
    const float* __restrict__ Xf0, const float* __restrict__ Xf1,
    const u16* __restrict__ Wb0, const u16* __restrict__ Wb1,
    const float* __restrict__ bias0, const float* __restrict__ bias1,
    u16* __restrict__ o0, u16* __restrict__ o1, float* __restrict__ of)
{
  constexpr int BN = (V==0)?128:64;
  constexpr int NT = BN/32;            // n-frags per wave
  constexpr bool AF = (V==0);
  constexpr bool BF = (V==1);

  __shared__ __align__(16) char As[AF?32768:16384];
  __shared__ __align__(16) char Bs[BF?(BN*256):(BN*128)];

  const float* Xa=nullptr; const u16* Aa=nullptr;
  const float* Xb=nullptr; const u16* Bb=nullptr;
  const float* bias; u16* outb=nullptr;
  if (V==0){
    const int z = blockIdx.z;
    Xa = z?Xf1:Xf0; Bb = z?Wb1:Wb0; bias = z?bias1:bias0; outb = z?o1:o0;
  } else if (V==1){ Aa = Wb0; Xb = Xf0; bias = bias0; outb = o0; }
  else            { Aa = Wb0; Bb = Wb1; bias = bias0; }

  const int m0 = blockIdx.x<<7, n0 = blockIdx.y*BN;
  const int tid = threadIdx.x, lane = tid&63, wv = tid>>6;
  const int wm = wv>>1, wn = wv&1, l15 = lane&15, g4 = lane>>4;

  f32x4 acc[4][NT] = {};

  #pragma unroll 1
  for (int kt=0; kt<1024; kt+=64){
    __syncthreads();
    if (AF) stage_f32 <128>(Xa + (size_t)m0*1024 + kt, 1024, As, wv, lane);
    else    stage_bf16<128>(Aa + (size_t)m0*1024 + kt, 1024, As, wv, lane);
    if (BF) stage_f32 <BN>(Xb + (size_t)n0*1024 + kt, 1024, Bs, wv, lane);
    else    stage_bf16<BN>(Bb + (size_t)n0*1024 + kt, 1024, Bs, wv, lane);
    __syncthreads();

    #pragma unroll
    for (int kb=0;kb<64;kb+=32){
      const int kcol = kb + (g4<<3);
      bf16x8 af[4], bf_[NT];
      #pragma unroll
      for (int t=0;t<4;++t){
        const int row = (wm<<6) + (t<<4) + l15;
        af[t] = AF ? frag_f32c(As, row, kb, lane) : frag_bf16(As, row, kcol);
      }
      #pragma unroll
      for (int t=0;t<NT;++t){
        const int row = wn*(BN>>1) + (t<<4) + l15;
        bf_[t] = BF ? frag_f32c(Bs, row, kb, lane) : frag_bf16(Bs, row, kcol);
      }
      __builtin_amdgcn_s_setprio(1);
      #pragma unroll
      for (int mt=0;mt<4;++mt)
        #pragma unroll
        for (int nt=0;nt<NT;++nt)
          acc[mt][nt] = MFMA(af[mt], bf_[nt], acc[mt][nt]);
      __builtin_amdgcn_s_setprio(0);
    }
  }

  f32x4 bmv[4];
  if (V==1){
    #pragma unroll
    for (int mt=0;mt<4;++mt)
      bmv[mt] = *(const f32x4*)(bias0 + m0 + (wm<<6) + (mt<<4) + (g4<<2));
  }
  #pragma unroll
  for (int nt=0;nt<NT;++nt){
    const int col = n0 + wn*(BN>>1) + (nt<<4) + l15;
    const float bvn = (V==1) ? 0.f : bias[col];
    #pragma unroll
    for (int mt=0;mt<4;++mt){
      const int mb = m0 + (wm<<6) + (mt<<4) + (g4<<2);
      f32x4 a = acc[mt][nt];
      #pragma unroll
      for (int j=0;j<4;++j){
        const float val = a[j] + ((V==1) ? bmv[mt][j] : bvn);
        if      (V==2) of  [(size_t)(mb+j)*1024 + col] = val;
        else if (V==1) outb[(size_t)(mb+j)*4096 + col] = f2bf(val);
        else           outb[(size_t)(mb+j)*1024 + col] = f2bf(val);
      }
    }
  }
}

// ---------------- flash attention (round-3 verified structure) ----------------
// qp/kp bf16 [B*S,E]; vt bf16 [E,B*S]. ctx bf16 [B*S,E].
// Block: 128 q-rows x (h,b); 4 waves x 32 rows. KV tiles 64, dbuf.
// Non-swapped QK^T; P via scalar u16 LDS writes + fence (proven-passing path).
__global__ __launch_bounds__(256) void attn_k(
    const u16* __restrict__ qp, const u16* __restrict__ kp, const u16* __restrict__ vt,
    const int* __restrict__ mask, u16* __restrict__ ctx)
{
  const int bid = blockIdx.x;
  const int wg  = (bid&7)*64 + (bid>>3);     // XCD-chunked (512 = 8*64, bijective)
  const int qt = wg&7, h = (wg>>3)&15, b = wg>>7;

  __shared__ __align__(16) u16 Qs[128*64];    // 16KB
  __shared__ __align__(16) u16 Ks[2][64*64];  // 16KB
  __shared__ __align__(16) u16 Vs[2][64*64];  // 16KB (rows=d, cols=key)
  __shared__ __align__(16) u16 Ps[4*32*64];   // 16KB per-wave P
  __shared__ __align__(16) float biasl[1024]; // 4KB

  const int tid = threadIdx.x, lane = tid&63, wv = tid>>6;
  const int hc = h<<6;

  { // mask -> additive bias (exp(-1e30)=0 kills masked keys exactly)
    const int4 mv = *(const int4*)(mask + (b<<10) + (tid<<2));
    float* bl = biasl + (tid<<2);
    bl[0] = mv.x ? 0.f : -1e30f;
    bl[1] = mv.y ? 0.f : -1e30f;
    bl[2] = mv.z ? 0.f : -1e30f;
    bl[3] = mv.w ? 0.f : -1e30f;
  }

  { // stage Q (128 x 64)
    const u16* Qg = qp + ((size_t)((b<<10) + (qt<<7)))*1024 + hc;
    #pragma unroll
    for (int i=0;i<4;++i){
      const int r0 = (wv<<5) + (i<<3);
      const int row = r0 + (lane>>3);
      const int c = ((lane&7) ^ (row&7)) << 3;
      gl16(Qg + (size_t)row*1024 + c, (char*)Qs + (r0<<7));
    }
  }

  const u16* Kg = kp + ((size_t)(b<<10))*1024 + hc;
  const u16* Vg = vt + ((size_t)hc)*4096 + (b<<10);

  auto stageKV = [&](int kt2, int bi){
    #pragma unroll
    for (int i=0;i<2;++i){
      const int r0 = (wv<<4) + (i<<3);
      const int row = r0 + (lane>>3);
      const int c = ((lane&7) ^ (row&7)) << 3;
      gl16(Kg + (size_t)((kt2<<6) + row)*1024 + c, (char*)Ks[bi] + (r0<<7));
      gl16(Vg + (size_t)row*4096 + (kt2<<6) + c,  (char*)Vs[bi] + (r0<<7));
    }
  };
  stageKV(0, 0);
  __syncthreads();

  f32x4 o[2][4] = {};
  float lr[2][4] = {};
  u16* Pw = Ps + (wv<<11);
  int cur = 0;

  #pragma unroll 1
  for (int kt=0; kt<16; ++kt){
    if (kt<15) stageKV(kt+1, cur^1);
    const char* Kc = (const char*)Ks[cur];
    const char* Vc = (const char*)Vs[cur];

    // S = Q K^T  (2 q-subtiles x 4 key-subtiles)
    f32x4 sc[2][4] = {};
    #pragma unroll
    for (int kb=0;kb<64;kb+=32){
      const int kcol = kb + ((lane>>4)<<3);
      bf16x8 kf[4];
      #pragma unroll
      for (int nt=0;nt<4;++nt) kf[nt] = frag_bf16(Kc, (nt<<4)+(lane&15), kcol);
      bf16x8 aq0 = frag_bf16((const char*)Qs, (wv<<5)+(lane&15), kcol);
      bf16x8 aq1 = frag_bf16((const char*)Qs, (wv<<5)+16+(lane&15), kcol);
      __builtin_amdgcn_s_setprio(1);
      #pragma unroll
      for (int nt=0;nt<4;++nt) sc[0][nt] = MFMA(aq0, kf[nt], sc[0][nt]);
      #pragma unroll
      for (int nt=0;nt<4;++nt) sc[1][nt] = MFMA(aq1, kf[nt], sc[1][nt]);
      __builtin_amdgcn_s_setprio(0);
    }

    // p = exp(s/8 + bias); masked -> exact 0. No max, no rescale.
    float bv4[4];
    #pragma unroll
    for (int nt=0;nt<4;++nt) bv4[nt] = biasl[(kt<<6)+(nt<<4)+(lane&15)];
    #pragma unroll
    for (int sub=0;sub<2;++sub)
      #pragma unroll
      for (int nt=0;nt<4;++nt){
        f32x4 s = sc[sub][nt];
        #pragma unroll
        for (int j=0;j<4;++j){
          const float p = __expf(fmaf(s[j], 0.125f, bv4[nt]));
          lr[sub][j] += p;
          *(u16*)((char*)Pw + swz((sub<<4)+((lane>>4)<<2)+j, (nt<<4)+(lane&15))) = f2bf(p);
        }
      }
    asm volatile("s_waitcnt lgkmcnt(0)" ::: "memory");
    __builtin_amdgcn_sched_barrier(0);

    // O += P V
    #pragma unroll
    for (int kb=0;kb<64;kb+=32){
      const int kcol = kb + ((lane>>4)<<3);
      bf16x8 vf[4];
      #pragma unroll
      for (int nt=0;nt<4;++nt) vf[nt] = frag_bf16(Vc, (nt<<4)+(lane&15), kcol);
      bf16x8 pa0 = frag_bf16((const char*)Pw, (lane&15), kcol);
      bf16x8 pa1 = frag_bf16((const char*)Pw, 16+(lane&15), kcol);
      __builtin_amdgcn_s_setprio(1);
      #pragma unroll
      for (int nt=0;nt<4;++nt) o[0][nt] = MFMA(pa0, vf[nt], o[0][nt]);
      #pragma unroll
      for (int nt=0;nt<4;++nt) o[1][nt] = MFMA(pa1, vf[nt], o[1][nt]);
      __builtin_amdgcn_s_setprio(0);
    }
    __syncthreads();
    cur ^= 1;
  }

  // epilogue: deferred row-sum reduce (keys spread over lane&15), normalize, write
  #pragma unroll
  for (int sub=0;sub<2;++sub)
    #pragma unroll
    for (int j=0;j<4;++j){
      float s = lr[sub][j];
      s += __shfl_xor(s,1); s += __shfl_xor(s,2);
      s += __shfl_xor(s,4); s += __shfl_xor(s,8);
      const float inv = 1.f / fmaxf(s, 1e-30f);
      const int row = (qt<<7) + (wv<<5) + (sub<<4) + ((lane>>4)<<2) + j;
      u16* crow = ctx + ((size_t)((b<<10)+row))*1024 + hc;
      #pragma unroll
      for (int nt=0;nt<4;++nt)
        crow[(nt<<4)+(lane&15)] = f2bf(o[sub][nt][j]*inv);
    }
}

extern "C" void kernel_launch(void* const* d_in, const int* in_sizes, int n_in,
                              void* d_out, int out_size, void* d_ws, size_t ws_size,
                              hipStream_t stream) {
  const float* q    = (const float*)d_in[0];
  const float* k    = (const float*)d_in[1];
  const float* v    = (const float*)d_in[2];
  const int*   mask = (const int*)  d_in[3];
  const float* Wq   = (const float*)d_in[4];
  const float* bq   = (const float*)d_in[5];
  const float* Wk   = (const float*)d_in[6];
  const float* bk   = (const float*)d_in[7];
  const float* Wo   = (const float*)d_in[8];
  const float* bo   = (const float*)d_in[9];
  float* out = (float*)d_out;

  // ws: wqb 2M | wkb 2M | wob 2M | qp 8M | kp 8M | vt 8M | ctx 8M = 38 MiB
  char* ws = (char*)d_ws;
  u16* wqb  = (u16*)(ws);
  u16* wkb  = (u16*)(ws +  2097152);
  u16* wob  = (u16*)(ws +  4194304);
  u16* qp   = (u16*)(ws +  6291456);
  u16* kp   = (u16*)(ws + 14680064);
  u16* vtb  = (u16*)(ws + 23068672);
  u16* ctxb = (u16*)(ws + 31457280);

  dim3 blk(256);
  cvtw_k<<<1536, blk, 0, stream>>>(Wq, Wk, Wo, wqb);
  // q,k projections -> bf16 row-major
  gemm_k<0><<<dim3(32,8,2), blk, 0, stream>>>(q, k, wqb, wkb, bq, bk, qp, kp, nullptr);
  // v projection transposed: vt = Wk @ v^T + bk (reference uses Wk/bk for v)
  gemm_k<1><<<dim3(8,64), blk, 0, stream>>>(v, nullptr, wkb, nullptr, bk, nullptr,
                                            vtb, nullptr, nullptr);
  attn_k<<<512, blk, 0, stream>>>(qp, kp, vtb, mask, ctxb);
  gemm_k<2><<<dim3(32,16), blk, 0, stream>>>(nullptr, nullptr, ctxb, wob, bo, nullptr,
                                             nullptr, nullptr, out);
}